// Round 6
// baseline (110.429 us; speedup 1.0000x reference)
//
#include <hip/hip_runtime.h>
#include <math.h>

#define N 4096
#define E 96
#define H 6
#define DH 16
#define G 64
#define CMAX 128          // max supported group size (mean 64, +8 sigma safe)
#define KSTR 19           // LDS row stride: odd stride -> <=2-way banks (free, m136)
#define NW 8              // waves per block
#define NT 512            // threads per block

// One block per (group, head, position-parity). Bucket build is DETERMINISTIC
// (ballot masks + prefix scan, no atomics) so both parity blocks of a (g,h)
// compute identical bucket arrays -> position parity partitions rows exactly.
__global__ __launch_bounds__(NT, 6) void fused_kernel(const float* __restrict__ feats,
                                                      const int* __restrict__ grp,
                                                      const float* __restrict__ w_in,
                                                      const float* __restrict__ b_in,
                                                      const float* __restrict__ w_out,
                                                      const float* __restrict__ w_cls,
                                                      float* __restrict__ part) {
    __shared__ float wl[48 * 100];        // w_in head slice (48 cols x 96), stride 100
    __shared__ float kh[CMAX * KSTR];
    __shared__ float vh[CMAX * KSTR];     // fully zero-filled, then rows < cnt overwritten
    __shared__ float qh[64 * KSTR];       // own-parity q rows, compact index j = r>>1
    __shared__ float ps[NW * CMAX];       // per-wave softmax weights
    __shared__ int   bucket[CMAX];
    __shared__ unsigned long long smask[64];   // per-chunk membership masks
    __shared__ int   scount[64];
    __shared__ int   soffs[64];
    __shared__ float wfh[DH];             // head slice of folded classifier
    __shared__ int   scnt;

    int g  = blockIdx.x & 63;
    int hh = blockIdx.x >> 6;             // 0..11
    int h  = hh >> 1;
    int hb = hh & 1;                      // position parity this block owns
    int tid = threadIdx.x, lane = tid & 63, wv = tid >> 6;

    // ---- Phase A: per-chunk ballot masks (deterministic chunk->wave mapping)
    #pragma unroll
    for (int c8 = 0; c8 < 8; ++c8) {
        int cc = wv * 8 + c8;                       // chunk 0..63
        bool mt = (grp[(cc << 6) + lane] == g);     // coalesced, L2-hot
        unsigned long long mask = __ballot(mt);
        if (lane == 0) { smask[cc] = mask; scount[cc] = __popcll(mask); }
    }

    // ---- stage w_in slice: {q,k,v} x 16 cols for this head
    for (int idx = tid; idx < 48 * 24; idx += NT) {
        int ci = idx / 24, j = idx % 24;
        int pp = ci >> 4, dd = ci & 15;
        int gcol = pp * E + h * DH + dd;
        *(float4*)(wl + ci * 100 + j * 4) = *(const float4*)(w_in + gcol * E + j * 4);
    }

    // ---- head slice of folded classifier: wfh[dd] = sum_u w_cls[u]*w_out[u][h*16+dd]
    if (wv == 7) {
        int dd = lane & 15, u4 = lane >> 4;
        float s = 0.f;
        for (int u = u4 * 24; u < u4 * 24 + 24; ++u)
            s += w_cls[u] * w_out[u * E + h * DH + dd];
        s += __shfl_xor(s, 16, 64);
        s += __shfl_xor(s, 32, 64);
        if (lane < DH) wfh[lane] = s;
    }
    __syncthreads();

    // ---- Phase B: wave 0 exclusive-scans chunk counts; waves 1..7 zero-fill vh
    if (wv == 0) {
        int v = scount[lane];
        int x = v;
        #pragma unroll
        for (int o = 1; o < 64; o <<= 1) {
            int y = __shfl_up(x, o, 64);
            if (lane >= o) x += y;
        }
        soffs[lane] = x - v;
        if (lane == 63) scnt = x;
    } else {
        for (int idx = tid - 64; idx < CMAX * KSTR; idx += NT - 64) vh[idx] = 0.f;
    }
    __syncthreads();

    int cnt = scnt; if (cnt > CMAX) cnt = CMAX;

    // ---- Phase C: deterministic scatter (identical in both parity blocks)
    #pragma unroll
    for (int c8 = 0; c8 < 8; ++c8) {
        int cc = wv * 8 + c8;
        unsigned long long mask = smask[cc];
        if ((mask >> lane) & 1ULL) {
            int pos = soffs[cc] + __popcll(mask & ((1ULL << lane) - 1ULL));
            if (pos < CMAX) bucket[pos] = (cc << 6) + lane;
        }
    }
    __syncthreads();

    int d = tid & 15, rr = tid >> 4;      // rr 0..31
    // ---- k,v for ALL group rows
    float bk = b_in[E + h * DH + d];
    float bv = b_in[2 * E + h * DH + d];
    const float4* wk  = (const float4*)(wl + (16 + d) * 100);
    const float4* wvp = (const float4*)(wl + (32 + d) * 100);
    #pragma unroll
    for (int p = 0; p < 4; ++p) {
        int s = rr + 32 * p;
        if (s < cnt) {
            const float4* fp = (const float4*)(feats + bucket[s] * E);
            float sk = 0.f, sv = 0.f;
            #pragma unroll
            for (int e4 = 0; e4 < 24; ++e4) {
                float4 f = fp[e4];
                float4 b = wk[e4], c = wvp[e4];
                sk += f.x*b.x + f.y*b.y + f.z*b.z + f.w*b.w;
                sv += f.x*c.x + f.y*c.y + f.z*c.z + f.w*c.w;
            }
            kh[s * KSTR + d] = sk + bk;
            vh[s * KSTR + d] = sv + bv;
        }
    }

    // ---- q for own-parity positions only (compact index j; position r = 2j+hb)
    float bq = b_in[h * DH + d];
    const float4* wq = (const float4*)(wl + d * 100);
    #pragma unroll
    for (int p = 0; p < 2; ++p) {
        int j = rr + 32 * p;
        int r = 2 * j + hb;
        if (r < cnt) {
            const float4* fp = (const float4*)(feats + bucket[r] * E);
            float sq = 0.f;
            #pragma unroll
            for (int e4 = 0; e4 < 24; ++e4) {
                float4 f = fp[e4];
                float4 a = wq[e4];
                sq += f.x*a.x + f.y*a.y + f.z*a.z + f.w*a.w;
            }
            qh[j * KSTR + d] = (sq + bq) * 0.25f;       // 1/sqrt(16)
        }
    }
    __syncthreads();

    // ---- attention: wave wv handles compact rows j = wv, wv+8, ...
    for (int j = wv; 2 * j + hb < cnt; j += NW) {
        int r = 2 * j + hb;
        float qv[16];
        #pragma unroll
        for (int e = 0; e < 16; ++e) qv[e] = qh[j * KSTR + e];   // broadcast

        float a0 = 0.f;
        #pragma unroll
        for (int e = 0; e < 16; ++e) a0 += qv[e] * kh[lane * KSTR + e];
        float s0 = (lane < cnt) ? a0 : -INFINITY;
        float s1 = -INFINITY;
        if (cnt > 64) {
            float a1 = 0.f;
            #pragma unroll
            for (int e = 0; e < 16; ++e) a1 += qv[e] * kh[(64 + lane) * KSTR + e];
            s1 = (64 + lane < cnt) ? a1 : -INFINITY;
        }

        float m = fmaxf(s0, s1);
        #pragma unroll
        for (int o = 32; o >= 1; o >>= 1) m = fmaxf(m, __shfl_xor(m, o, 64));
        float p0 = __expf(s0 - m);                      // masked lanes -> 0
        float p1 = (cnt > 64) ? __expf(s1 - m) : 0.f;
        float l = p0 + p1;
        #pragma unroll
        for (int o = 32; o >= 1; o >>= 1) l += __shfl_xor(l, o, 64);
        ps[wv * CMAX + lane] = p0;
        ps[wv * CMAX + 64 + lane] = p1;

        // PV: fixed-trip, fully unrolled; ps==0 / vh==0 cover padding
        int mm4 = lane >> 4, dd = lane & 15;
        float acc = 0.f;
        #pragma unroll
        for (int k = 0; k < 16; ++k) {
            int m2 = mm4 + 4 * k;
            acc += ps[wv * CMAX + m2] * vh[m2 * KSTR + dd];
        }
        if (cnt > 64) {
            #pragma unroll
            for (int k = 16; k < 32; ++k) {
                int m2 = mm4 + 4 * k;
                acc += ps[wv * CMAX + m2] * vh[m2 * KSTR + dd];
            }
        }
        acc += __shfl_xor(acc, 16, 64);
        acc += __shfl_xor(acc, 32, 64);

        // partial logit for this head
        float pt = (acc / l) * wfh[dd];
        pt += __shfl_xor(pt, 1, 64);
        pt += __shfl_xor(pt, 2, 64);
        pt += __shfl_xor(pt, 4, 64);
        pt += __shfl_xor(pt, 8, 64);
        if (lane == 0) part[bucket[r] * 8 + h] = pt;    // exactly-once write, no atomic
    }
}

// ---------------- K2: sum 6 head partials + folded bias, sigmoid
__global__ __launch_bounds__(512) void sigmoid_kernel(const float* __restrict__ part,
                                                      const float* __restrict__ w_cls,
                                                      const float* __restrict__ b_out,
                                                      const float* __restrict__ b_cls,
                                                      float* __restrict__ out) {
    __shared__ float sbias;
    int tid = threadIdx.x;
    if (tid < 64) {
        float s = w_cls[tid] * b_out[tid];
        if (tid < 32) s += w_cls[tid + 64] * b_out[tid + 64];
        #pragma unroll
        for (int o = 32; o >= 1; o >>= 1) s += __shfl_xor(s, o, 64);
        if (tid == 0) sbias = s + b_cls[0];
    }
    __syncthreads();
    int i = blockIdx.x * 512 + tid;
    const float4* p = (const float4*)(part + i * 8);
    float4 u = p[0], v = p[1];
    float s = u.x + u.y + u.z + u.w + v.x + v.y + sbias;
    out[i] = 1.f / (1.f + __expf(-s));
}

extern "C" void kernel_launch(void* const* d_in, const int* in_sizes, int n_in,
                              void* d_out, int out_size, void* d_ws, size_t ws_size,
                              hipStream_t stream) {
    const float* feats = (const float*)d_in[0];
    const int*   grp   = (const int*)  d_in[1];
    const float* w_in  = (const float*)d_in[2];
    const float* b_in  = (const float*)d_in[3];
    const float* w_out = (const float*)d_in[4];
    const float* b_out = (const float*)d_in[5];
    const float* w_cls = (const float*)d_in[6];
    const float* b_cls = (const float*)d_in[7];
    float* out = (float*)d_out;

    float* part = (float*)d_ws;           // N*8 floats, every (row,head<6) slot written

    fused_kernel<<<G * H * 2, NT, 0, stream>>>(feats, grp, w_in, b_in, w_out, w_cls, part);
    sigmoid_kernel<<<N / 512, 512, 0, stream>>>(part, w_cls, b_out, b_cls, out);
}